// Round 9
// baseline (3258.591 us; speedup 1.0000x reference)
//
#include <hip/hip_runtime.h>
#include <stdint.h>

typedef __attribute__((ext_vector_type(8))) short short8;
typedef __attribute__((ext_vector_type(4))) float floatx4;
typedef __attribute__((ext_vector_type(4))) unsigned int uintx4;

#define DEVINL __device__ __forceinline__

DEVINL unsigned short f2bf(float f) {
    unsigned int u = __float_as_uint(f);
    u += 0x7FFFu + ((u >> 16) & 1u);
    return (unsigned short)(u >> 16);
}
DEVINL float bf2f(unsigned short h) {
    return __uint_as_float(((unsigned int)h) << 16);
}
DEVINL float sigf(float x)     { return 1.0f / (1.0f + __expf(-x)); }
DEVINL float tanhfast(float x) { return 2.0f / (1.0f + __expf(-2.0f * x)) - 1.0f; }

// ---------------- problem constants ----------------
constexpr int L_SEQ = 256, BATCH = 16, HID = 800, NGATE = 3200, DIN = 42, NALPHA = 20;
constexpr int HSLOT = BATCH * HID;          // 12800 elements per time slot
constexpr int NBLK_SCAN = 200;              // 2 dirs x 100 j-chunks (8 hidden units each)

// ---------------- workspace layout (bytes) ----------------
constexpr size_t OFF_FLAGS   = 0;                                   // reserved (unused)
constexpr size_t SZ_FLAGS    = 131072;
constexpr size_t SZ_WHH_L    = 10240000;                            // per layer: 2*3200*800*2B
constexpr size_t OFF_WHH_HI  = SZ_FLAGS;                            // 2 layers
constexpr size_t OFF_WHH_LO  = OFF_WHH_HI + 2 * SZ_WHH_L;
constexpr size_t SZ_WIH1     = 20480000;                            // 2*3200*1600*2B
constexpr size_t OFF_WIH1_HI = OFF_WHH_LO + 2 * SZ_WHH_L;
constexpr size_t OFF_WIH1_LO = OFF_WIH1_HI + SZ_WIH1;
constexpr size_t OFF_PRE     = OFF_WIH1_LO + SZ_WIH1;               // fp32, shared pre0/pre1
constexpr size_t SZ_PRE      = (size_t)2 * L_SEQ * BATCH * NGATE * 4;  // 104,857,600
constexpr size_t SZ_HP       = (size_t)257 * HSLOT * 4;             // 13,158,400 per packed buf
constexpr size_t OFF_H       = OFF_PRE + SZ_PRE;                    // 4 bufs: F, B, 2F, 2B
constexpr size_t OFF_ANG     = OFF_H + 4 * SZ_HP;                   // 256*16*3 fp32
// total ~228.6 MiB

// =====================================================================
// Pack W_hh (fp32 [2][3200][800]) into hi/lo MFMA B-fragment streams.
// =====================================================================
__global__ __launch_bounds__(256) void pack_whh_kernel(
    const float* __restrict__ w0, const float* __restrict__ w1,
    unsigned short* __restrict__ hi, unsigned short* __restrict__ lo)
{
    size_t g = (size_t)blockIdx.x * 256 + threadIdx.x;   // 1,280,000 total
    if (g >= 1280000) return;
    int l = (int)(g & 63);
    size_t gg = g >> 6;                                   // 20000 fragment ids
    int kk = (int)(gg % 25); gg /= 25;
    int nt = (int)(gg % 2);  gg /= 2;
    int jc = (int)(gg % 100); gg /= 100;
    int d  = (int)(gg % 2);
    int layer = (int)(gg / 2);
    const float* W = layer ? w1 : w0;
    int lr = nt * 16 + (l & 15);
    int gate = lr >> 3, jj = lr & 7;
    int r  = gate * 800 + jc * 8 + jj;
    int k0 = kk * 32 + (l >> 4) * 8;
    const float* s = W + ((size_t)d * NGATE + r) * HID + k0;
    short8 vh, vl;
    #pragma unroll
    for (int j = 0; j < 8; ++j) {
        float w = s[j];
        unsigned short h = f2bf(w);
        vh[j] = (short)h;
        vl[j] = (short)f2bf(w - bf2f(h));
    }
    size_t idx = (size_t)layer * 640000 + ((size_t)d * 100 + jc) * 3200
               + (size_t)(nt * 25 + kk) * 64 + l;
    ((short8*)hi)[idx] = vh;
    ((short8*)lo)[idx] = vl;
}

// =====================================================================
// fp32 -> hi/lo bf16 conversion of w_ih_l1 (flat [2][3200][1600]).
// =====================================================================
__global__ __launch_bounds__(256) void conv_wih1_kernel(
    const float* __restrict__ w, unsigned short* __restrict__ hi,
    unsigned short* __restrict__ lo)
{
    size_t g = (size_t)blockIdx.x * 256 + threadIdx.x;   // 1,280,000 groups of 8
    if (g >= 1280000) return;
    const float* s = w + g * 8;
    short8 vh, vl;
    #pragma unroll
    for (int j = 0; j < 8; ++j) {
        float x = s[j];
        unsigned short h = f2bf(x);
        vh[j] = (short)h;
        vl[j] = (short)f2bf(x - bf2f(h));
    }
    ((short8*)hi)[g] = vh;
    ((short8*)lo)[g] = vl;
}

// =====================================================================
// pre0[d][t][b][r] = x[t,b,:] @ w_ih_l0[d].T + b_l0[d]   (fp32 out)
// =====================================================================
__global__ __launch_bounds__(256) void pre0_kernel(
    const float* __restrict__ x, const float* __restrict__ wih0,
    const float* __restrict__ b0, float* __restrict__ pre0)
{
    int bid = blockIdx.x;
    int d = bid / 800; int rem = bid % 800;
    int rc = rem / 8, tc = rem % 8;
    int rbase = rc * 32, tbase = tc * 32;
    __shared__ float Wc[32][DIN];
    __shared__ float bias[32];
    __shared__ float xb[BATCH][DIN];
    int tid = threadIdx.x;
    for (int idx = tid; idx < 32 * DIN; idx += 256) {
        int rl = idx / DIN, k = idx % DIN;
        Wc[rl][k] = wih0[((size_t)d * NGATE + rbase + rl) * DIN + k];
    }
    if (tid < 32) bias[tid] = b0[d * NGATE + rbase + tid];
    __syncthreads();
    for (int tt = 0; tt < 32; ++tt) {
        int t = tbase + tt;
        for (int idx = tid; idx < BATCH * DIN; idx += 256) {
            int bb = idx / DIN, k = idx % DIN;
            xb[bb][k] = x[((size_t)bb * L_SEQ + t) * DIN + k];
        }
        __syncthreads();
        for (int o = tid; o < 512; o += 256) {
            int bb = o >> 5, rl = o & 31;
            float s = bias[rl];
            #pragma unroll 6
            for (int k = 0; k < DIN; ++k) s += xb[bb][k] * Wc[rl][k];
            pre0[((size_t)(d * L_SEQ + t) * BATCH + bb) * NGATE + rbase + rl] = s;
        }
        __syncthreads();
    }
}

// =====================================================================
// Forced-batch system-scope loads: all dwordx4 loads issued in one asm
// block (single vmcnt wait). Early-clobber outputs prevent addr aliasing.
// k-quarter variants: 14 loads (7 kk groups) and 12 loads (6 kk groups).
// =====================================================================
DEVINL void batch_load_14(const uint32_t* base, uintx4* pk) {
    asm volatile(
        "global_load_dwordx4 %0, %14, off sc0 sc1\n\t"
        "global_load_dwordx4 %1, %14, off offset:16 sc0 sc1\n\t"
        "global_load_dwordx4 %2, %14, off offset:128 sc0 sc1\n\t"
        "global_load_dwordx4 %3, %14, off offset:144 sc0 sc1\n\t"
        "global_load_dwordx4 %4, %14, off offset:256 sc0 sc1\n\t"
        "global_load_dwordx4 %5, %14, off offset:272 sc0 sc1\n\t"
        "global_load_dwordx4 %6, %14, off offset:384 sc0 sc1\n\t"
        "global_load_dwordx4 %7, %14, off offset:400 sc0 sc1\n\t"
        "global_load_dwordx4 %8, %14, off offset:512 sc0 sc1\n\t"
        "global_load_dwordx4 %9, %14, off offset:528 sc0 sc1\n\t"
        "global_load_dwordx4 %10, %14, off offset:640 sc0 sc1\n\t"
        "global_load_dwordx4 %11, %14, off offset:656 sc0 sc1\n\t"
        "global_load_dwordx4 %12, %14, off offset:768 sc0 sc1\n\t"
        "global_load_dwordx4 %13, %14, off offset:784 sc0 sc1\n\t"
        "s_waitcnt vmcnt(0)"
        : "=&v"(pk[0]), "=&v"(pk[1]), "=&v"(pk[2]), "=&v"(pk[3]),
          "=&v"(pk[4]), "=&v"(pk[5]), "=&v"(pk[6]), "=&v"(pk[7]),
          "=&v"(pk[8]), "=&v"(pk[9]), "=&v"(pk[10]), "=&v"(pk[11]),
          "=&v"(pk[12]), "=&v"(pk[13])
        : "v"(base)
        : "memory");
}

DEVINL void batch_load_12(const uint32_t* base, uintx4* pk) {
    asm volatile(
        "global_load_dwordx4 %0, %12, off sc0 sc1\n\t"
        "global_load_dwordx4 %1, %12, off offset:16 sc0 sc1\n\t"
        "global_load_dwordx4 %2, %12, off offset:128 sc0 sc1\n\t"
        "global_load_dwordx4 %3, %12, off offset:144 sc0 sc1\n\t"
        "global_load_dwordx4 %4, %12, off offset:256 sc0 sc1\n\t"
        "global_load_dwordx4 %5, %12, off offset:272 sc0 sc1\n\t"
        "global_load_dwordx4 %6, %12, off offset:384 sc0 sc1\n\t"
        "global_load_dwordx4 %7, %12, off offset:400 sc0 sc1\n\t"
        "global_load_dwordx4 %8, %12, off offset:512 sc0 sc1\n\t"
        "global_load_dwordx4 %9, %12, off offset:528 sc0 sc1\n\t"
        "global_load_dwordx4 %10, %12, off offset:640 sc0 sc1\n\t"
        "global_load_dwordx4 %11, %12, off offset:656 sc0 sc1\n\t"
        "s_waitcnt vmcnt(0)"
        : "=&v"(pk[0]), "=&v"(pk[1]), "=&v"(pk[2]), "=&v"(pk[3]),
          "=&v"(pk[4]), "=&v"(pk[5]), "=&v"(pk[6]), "=&v"(pk[7]),
          "=&v"(pk[8]), "=&v"(pk[9]), "=&v"(pk[10]), "=&v"(pk[11])
        : "v"(base)
        : "memory");
}

DEVINL void unpack_u44(uintx4 p0, uintx4 p1, short8& ah, short8& al) {
    ah[0]=(short)(p0.x&0xffffu); al[0]=(short)(p0.x>>16);
    ah[1]=(short)(p0.y&0xffffu); al[1]=(short)(p0.y>>16);
    ah[2]=(short)(p0.z&0xffffu); al[2]=(short)(p0.z>>16);
    ah[3]=(short)(p0.w&0xffffu); al[3]=(short)(p0.w>>16);
    ah[4]=(short)(p1.x&0xffffu); al[4]=(short)(p1.x>>16);
    ah[5]=(short)(p1.y&0xffffu); al[5]=(short)(p1.y>>16);
    ah[6]=(short)(p1.z&0xffffu); al[6]=(short)(p1.z>>16);
    ah[7]=(short)(p1.w&0xffffu); al[7]=(short)(p1.w>>16);
}

// k-quarter MFMA: one wave computes BOTH nt output tiles over its kk range.
template<int CNT, int KST>
DEVINL void mfma_k2(const uintx4* pk,
                    const short8* __restrict__ wH,
                    const short8* __restrict__ wL, int lane,
                    floatx4& out0, floatx4& out1)
{
    floatx4 p0 = {0.f,0.f,0.f,0.f}, q0 = {0.f,0.f,0.f,0.f};
    floatx4 p1 = {0.f,0.f,0.f,0.f}, q1 = {0.f,0.f,0.f,0.f};
    #pragma unroll
    for (int i = 0; i < CNT; ++i) {
        short8 ah, al;
        unpack_u44(pk[2 * i], pk[2 * i + 1], ah, al);
        int kk = KST + i;
        short8 bh0 = wH[(0 * 25 + kk) * 64 + lane];
        short8 bl0 = wL[(0 * 25 + kk) * 64 + lane];
        short8 bh1 = wH[(1 * 25 + kk) * 64 + lane];
        short8 bl1 = wL[(1 * 25 + kk) * 64 + lane];
        p0 = __builtin_amdgcn_mfma_f32_16x16x32_bf16(ah, bh0, p0, 0, 0, 0);
        q0 = __builtin_amdgcn_mfma_f32_16x16x32_bf16(ah, bl0, q0, 0, 0, 0);
        q0 = __builtin_amdgcn_mfma_f32_16x16x32_bf16(al, bh0, q0, 0, 0, 0);
        p1 = __builtin_amdgcn_mfma_f32_16x16x32_bf16(ah, bh1, p1, 0, 0, 0);
        q1 = __builtin_amdgcn_mfma_f32_16x16x32_bf16(ah, bl1, q1, 0, 0, 0);
        q1 = __builtin_amdgcn_mfma_f32_16x16x32_bf16(al, bh1, q1, 0, 0, 0);
    }
    out0 = p0 + q0;
    out1 = p1 + q1;
}

// =====================================================================
// Persistent bidirectional LSTM scan (split-precision bf16 hi/lo).
// R17 scan == R16 scan EXACTLY (measured 1124 us, best):
//  - sentinel protocol (data IS the signal), 4-way K-split dedup,
//  - confirmed-mask scattered poll with s_sleep(2) backoff,
//  - post-MFMA acc-NaN retry (retries rare).
// =====================================================================
__global__ __launch_bounds__(256, 1) void scan_kernel(
    const unsigned short* __restrict__ wpackH,
    const unsigned short* __restrict__ wpackL,
    const float* __restrict__ pre,              // [d][t][b][3200] fp32
    uint32_t* hFP, uint32_t* hBP)               // packed h archives [257][16][800]
{
    __shared__ __align__(16) unsigned short wldsH[25600];   // 51.2 KB
    __shared__ __align__(16) unsigned short wldsL[25600];   // 51.2 KB
    __shared__ __align__(16) float exch[2][2][4][64][4];    // [par][nt][kq][lane][reg]
    __shared__ float cbuf[128];
    int tid = threadIdx.x;
    int bid = blockIdx.x;
    int d = bid / 100, jc = bid % 100;

    {   // load weight fragments once
        const short8* sh = (const short8*)wpackH + ((size_t)d * 100 + jc) * 3200;
        const short8* sl = (const short8*)wpackL + ((size_t)d * 100 + jc) * 3200;
        short8* dh = (short8*)wldsH;
        short8* dl = (short8*)wldsL;
        for (int i = tid; i < 3200; i += 256) { dh[i] = sh[i]; dl[i] = sl[i]; }
    }
    if (tid < 128) cbuf[tid] = 0.0f;
    __syncthreads();

    int lane = tid & 63, w = tid >> 6;          // w = k-quarter index
    int st = 6 * w + (w > 0 ? 1 : 0);           // kkStart: {0,7,13,19}
    int bA = lane & 15, q = lane >> 4;
    int fb = (tid >> 3) & 15, fj = tid & 7;     // fuse indices (tid<128)

    uint32_t* hOutP = d ? hBP : hFP;
    const uint32_t* hInP = d ? hBP : hFP;
    const short8* wH8 = (const short8*)wldsH;
    const short8* wL8 = (const short8*)wldsL;

    // Poll setup: wave w's k-range [st*32, (st+CNT)*32) is produced by
    // jc blocks [jcBase, jcBase+npoll). Lane l checks jc jx's first word
    // (batch jx&15 scatters lines). Loop-invariant offset within a slot.
    int npoll = (w == 0) ? 28 : 24;
    int jcBase = (w == 0) ? 0 : (4 + 24 * w);   // {0,28,52,76}
    int jx = jcBase + ((lane < npoll) ? lane : 0);
    size_t pofs = (size_t)(jx & 15) * HID + (size_t)jx * 8;

    for (int s = 0; s < L_SEQ; ++s) {
        int t = d ? (L_SEQ - 1 - s) : s;
        int islot = d ? (t + 1) : t;
        const uint32_t* slotBase = hInP + (size_t)islot * HSLOT;
        const uint32_t* base = slotBase + bA * HID + st * 32 + q * 8;

        // prefetch pre gate values (independent of h) before waiting
        float pv[4];
        if (tid < 128) {
            const float* pp = pre + ((size_t)(d * L_SEQ + t) * BATCH + fb) * NGATE
                            + jc * 8 + fj;
            #pragma unroll
            for (int gate = 0; gate < 4; ++gate) pv[gate] = pp[gate * 800];
        }

        // ---- arrival poll on the h data itself (confirmed-mask + backoff) ----
        {
            const uint32_t* pw = slotBase + pofs;
            bool need = (lane < npoll);
            for (;;) {
                if (need) {
                    uint32_t v = __hip_atomic_load(pw, __ATOMIC_RELAXED,
                                                   __HIP_MEMORY_SCOPE_AGENT);
                    need = (v == 0xFFFFFFFFu);
                }
                if (!__any(need)) break;
                __builtin_amdgcn_s_sleep(2);
            }
        }

        // ---- batch load + split MFMA; NaN acc => raced a straggler => retry
        uintx4 pk[14];
        floatx4 acc0, acc1;
        for (;;) {
            if (w == 0) {
                batch_load_14(base, pk);
                mfma_k2<7, 0 >(pk, wH8, wL8, lane, acc0, acc1);
            } else if (w == 1) {
                batch_load_12(base, pk);
                mfma_k2<6, 7 >(pk, wH8, wL8, lane, acc0, acc1);
            } else if (w == 2) {
                batch_load_12(base, pk);
                mfma_k2<6, 13>(pk, wH8, wL8, lane, acc0, acc1);
            } else {
                batch_load_12(base, pk);
                mfma_k2<6, 19>(pk, wH8, wL8, lane, acc0, acc1);
            }
            bool bad = (acc0[0] != acc0[0]) || (acc0[1] != acc0[1])
                     || (acc0[2] != acc0[2]) || (acc0[3] != acc0[3])
                     || (acc1[0] != acc1[0]) || (acc1[1] != acc1[1])
                     || (acc1[2] != acc1[2]) || (acc1[3] != acc1[3]);
            if (!__any(bad)) break;
        }

        int p = s & 1;
        *(floatx4*)&exch[p][0][w][lane][0] = acc0;
        *(floatx4*)&exch[p][1][w][lane][0] = acc1;
        __syncthreads();     // the ONE barrier per step

        if (tid < 128) {
            float G[4];
            #pragma unroll
            for (int gate = 0; gate < 4; ++gate) {
                int lr = gate * 8 + fj;
                int nt2 = lr >> 4, n = lr & 15;
                int ln = ((fb >> 2) << 4) | n;
                int rg = fb & 3;
                G[gate] = pv[gate]
                        + exch[p][nt2][0][ln][rg] + exch[p][nt2][1][ln][rg]
                        + exch[p][nt2][2][ln][rg] + exch[p][nt2][3][ln][rg];
            }
            float i_ = sigf(G[0]), f_ = sigf(G[1]);
            float g_ = tanhfast(G[2]), o_ = sigf(G[3]);
            float c = f_ * cbuf[tid] + i_ * g_;
            cbuf[tid] = c;
            float h = o_ * tanhfast(c);
            int oslot = d ? t : (t + 1);
            size_t oidx = (size_t)oslot * HSLOT + fb * HID + jc * 8 + fj;
            unsigned short hh = f2bf(h);
            uint32_t pko = (uint32_t)hh
                         | ((uint32_t)f2bf(h - bf2f(hh)) << 16);
            __hip_atomic_store(&hOutP[oidx], pko, __ATOMIC_RELAXED,
                               __HIP_MEMORY_SCOPE_AGENT);
            // no drain, no flag: consumers poll the data itself
        }
        // no trailing barrier: exch double-buffered; next-step barrier orders reuse
    }
}

// =====================================================================
// pre1[d][t][b][r] = concat(h1f[t], h1b[t]) @ w_ih_l1[d].T + b_l1[d]  (fp32)
// R17: 256x128-tile split-precision MFMA GEMM (was 128x128).
//   LLC read traffic: A re-read x25 (unchanged), B re-read x32 -> x16:
//   total 1.96 GB -> 1.31 GB (-33%), and 2x MFMA work per staged byte.
//   Same register-prefetch pipeline; A-unpack hoisted, B inner loop.
//   Grid 2*16*25 = 800 blocks.  LDS 57.3 KB.
// =====================================================================
__global__ __launch_bounds__(256, 1) void gemm_pre1_kernel(
    const uint32_t* __restrict__ hFP, const uint32_t* __restrict__ hBP,
    const unsigned short* __restrict__ wih1H, const unsigned short* __restrict__ wih1L,
    const float* __restrict__ b1, float* __restrict__ pre1)
{
    int bid = blockIdx.x;
    int d = bid / 400; int rst = bid % 400;
    int mblk = rst / 25, nblk = rst % 25;
    __shared__ __align__(16) uint32_t       Au[256][36];   // packed h (hi|lo<<16), 36.9KB
    __shared__ __align__(16) unsigned short BH[128][40];   // 10.2KB
    __shared__ __align__(16) unsigned short BL[128][40];   // 10.2KB
    int tid = threadIdx.x, lane = tid & 63, w = tid >> 6;
    floatx4 acc[4][8] = {};
    int m_row = mblk * 256 + tid;               // A staging: 1 thread/row, 32 k-words
    int t = m_row >> 4, bb = m_row & 15;
    int brow = tid >> 1, bhalf = tid & 1;       // B staging: 2 threads/row
    int la = lane & 15, q = lane >> 4, q8 = q * 8;

    uintx4 ra[8];
    short8 rbh[2], rbl[2];

    auto LOAD = [&](int kk) {
        int k0 = kk * 32;
        size_t aoff = (kk < 25)
            ? ((size_t)(t + 1) * HSLOT + bb * HID + k0)
            : ((size_t)t * HSLOT + bb * HID + (k0 - 800));
        const uintx4* ap = (const uintx4*)(((kk < 25) ? hFP : hBP) + aoff);
        #pragma unroll
        for (int i = 0; i < 8; ++i) ra[i] = ap[i];
        size_t boff = ((size_t)d * NGATE + nblk * 128 + brow) * 1600
                    + (size_t)kk * 32 + bhalf * 16;
        const short8* bh = (const short8*)(wih1H + boff);
        const short8* bl = (const short8*)(wih1L + boff);
        rbh[0] = bh[0]; rbh[1] = bh[1];
        rbl[0] = bl[0]; rbl[1] = bl[1];
    };

    LOAD(0);
    for (int kk = 0; kk < 50; ++kk) {
        {   // commit staged regs to LDS
            uintx4* da = (uintx4*)&Au[tid][0];
            #pragma unroll
            for (int i = 0; i < 8; ++i) da[i] = ra[i];
            short8* dh = (short8*)&BH[brow][bhalf * 16];
            dh[0] = rbh[0]; dh[1] = rbh[1];
            short8* dl = (short8*)&BL[brow][bhalf * 16];
            dl[0] = rbl[0]; dl[1] = rbl[1];
        }
        __syncthreads();
        if (kk < 49) LOAD(kk + 1);          // global latency hides under MFMAs
        // hoisted A-fragment unpack (wave w owns M-rows w*64..w*64+63)
        short8 ahf[4], alf[4];
        #pragma unroll
        for (int ms = 0; ms < 4; ++ms) {
            const uintx4* pa = (const uintx4*)&Au[w * 64 + ms * 16 + la][q8];
            unpack_u44(pa[0], pa[1], ahf[ms], alf[ms]);
        }
        #pragma unroll
        for (int ns = 0; ns < 8; ++ns) {
            short8 fbh = *(const short8*)&BH[ns * 16 + la][q8];
            short8 fbl = *(const short8*)&BL[ns * 16 + la][q8];
            #pragma unroll
            for (int ms = 0; ms < 4; ++ms) {
                acc[ms][ns] = __builtin_amdgcn_mfma_f32_16x16x32_bf16(ahf[ms], fbh, acc[ms][ns], 0, 0, 0);
                acc[ms][ns] = __builtin_amdgcn_mfma_f32_16x16x32_bf16(ahf[ms], fbl, acc[ms][ns], 0, 0, 0);
                acc[ms][ns] = __builtin_amdgcn_mfma_f32_16x16x32_bf16(alf[ms], fbh, acc[ms][ns], 0, 0, 0);
            }
        }
        __syncthreads();
    }
    #pragma unroll
    for (int ms = 0; ms < 4; ++ms)
        #pragma unroll
        for (int ns = 0; ns < 8; ++ns)
            #pragma unroll
            for (int rg = 0; rg < 4; ++rg) {
                int m = mblk * 256 + w * 64 + ms * 16 + q * 4 + rg;
                int t2 = m >> 4, b2 = m & 15;
                int r = nblk * 128 + ns * 16 + la;
                float val = acc[ms][ns][rg] + b1[d * NGATE + r];
                pre1[((size_t)(d * L_SEQ + t2) * BATCH + b2) * NGATE + r] = val;
            }
}

// =====================================================================
// Head: logits -> softmax -> torsion angles.  One block per t.
// =====================================================================
__global__ __launch_bounds__(256) void head_kernel(
    const uint32_t* __restrict__ h2FP, const uint32_t* __restrict__ h2BP,
    const float* __restrict__ wlin, const float* __restrict__ blin,
    const float* __restrict__ alphabet, float* __restrict__ ang)
{
    int t = blockIdx.x, tid = threadIdx.x;
    __shared__ float lg[BATCH * NALPHA];
    __shared__ float probs[BATCH * NALPHA];
    for (int i = tid; i < BATCH * NALPHA; i += 256) {
        int a = i % NALPHA, b = i / NALPHA;
        size_t fo = (size_t)(t + 1) * HSLOT + b * HID;
        size_t bo = (size_t)t * HSLOT + b * HID;
        const float* wa = wlin + (size_t)a * 1600;
        float s = blin[a];
        #pragma unroll 4
        for (int k = 0; k < HID; ++k) {
            uint32_t uf = h2FP[fo + k], ub = h2BP[bo + k];
            float hf = bf2f((unsigned short)uf) + bf2f((unsigned short)(uf >> 16));
            float hb = bf2f((unsigned short)ub) + bf2f((unsigned short)(ub >> 16));
            s += hf * wa[k] + hb * wa[800 + k];
        }
        lg[b * NALPHA + a] = s;
    }
    __syncthreads();
    if (tid < BATCH) {
        int b = tid;
        float mx = -1e30f;
        for (int a = 0; a < NALPHA; ++a) mx = fmaxf(mx, lg[b * NALPHA + a]);
        float sum = 0.f;
        for (int a = 0; a < NALPHA; ++a) {
            float e = __expf(lg[b * NALPHA + a] - mx);
            probs[b * NALPHA + a] = e; sum += e;
        }
        float inv = 1.0f / sum;
        for (int a = 0; a < NALPHA; ++a) probs[b * NALPHA + a] *= inv;
    }
    __syncthreads();
    if (tid < BATCH * 3) {
        int b = tid / 3, i = tid % 3;
        float ss = 0.f, cc = 0.f;
        for (int a = 0; a < NALPHA; ++a) {
            float al = alphabet[a * 3 + i], p = probs[b * NALPHA + a];
            ss += p * sinf(al); cc += p * cosf(al);
        }
        ang[((size_t)t * BATCH + b) * 3 + i] = atan2f(ss, cc);
    }
}

// =====================================================================
// Sequential NeRF coordinate chain. One block; lane b handles batch b.
// Fast HW trig (__sinf/__cosf, P in [-pi,pi]) + rsqrtf.  [R13, kept]
// =====================================================================
__global__ __launch_bounds__(64) void coords_kernel(
    const float* __restrict__ ang, float* __restrict__ out)
{
    int b = threadIdx.x;
    if (b >= BATCH) return;
    const float LENS[3] = {145.801f, 152.326f, 132.868f};
    const float ANGS[3] = {2.124f, 1.941f, 2.028f};
    float sT[3], cT[3];
    #pragma unroll
    for (int i = 0; i < 3; ++i) { sT[i] = sinf(ANGS[i]); cT[i] = cosf(ANGS[i]); }
    float Ax = 0.f, Ay = 0.f, Az = 1.f;
    float Bx = 0.f, By = 1.f, Bz = 0.f;
    float Cx = 1.f, Cy = 0.f, Cz = 0.f;
    out[((size_t)0 * BATCH + b) * 3 + 0] = 0.f; out[((size_t)0 * BATCH + b) * 3 + 1] = 0.f; out[((size_t)0 * BATCH + b) * 3 + 2] = 1.f;
    out[((size_t)1 * BATCH + b) * 3 + 0] = 0.f; out[((size_t)1 * BATCH + b) * 3 + 1] = 1.f; out[((size_t)1 * BATCH + b) * 3 + 2] = 0.f;
    out[((size_t)2 * BATCH + b) * 3 + 0] = 1.f; out[((size_t)2 * BATCH + b) * 3 + 1] = 0.f; out[((size_t)2 * BATCH + b) * 3 + 2] = 0.f;
    for (int t = 0; t < L_SEQ; ++t) {
        #pragma unroll
        for (int i = 0; i < 3; ++i) {
            float P = ang[((size_t)t * BATCH + b) * 3 + i];
            float R = LENS[i];
            float sP = __sinf(P), cP = __cosf(P);
            float D2x = -R * cT[i];
            float D2y = R * cP * sT[i];
            float D2z = R * sP * sT[i];
            float bx = Cx - Bx, by = Cy - By, bz = Cz - Bz;
            float binv = rsqrtf(bx * bx + by * by + bz * bz);
            bx *= binv; by *= binv; bz *= binv;
            float ux = Bx - Ax, uy = By - Ay, uz = Bz - Az;
            float nx = uy * bz - uz * by;
            float ny = uz * bx - ux * bz;
            float nz = ux * by - uy * bx;
            float ninv = rsqrtf(nx * nx + ny * ny + nz * nz);
            nx *= ninv; ny *= ninv; nz *= ninv;
            float cxx = ny * bz - nz * by;
            float cxy = nz * bx - nx * bz;
            float cxz = nx * by - ny * bx;
            float Dx = bx * D2x + cxx * D2y + nx * D2z + Cx;
            float Dy = by * D2x + cxy * D2y + ny * D2z + Cy;
            float Dz = bz * D2x + cxz * D2y + nz * D2z + Cz;
            size_t orow = 3 + (size_t)t * 3 + i;
            out[(orow * BATCH + b) * 3 + 0] = Dx;
            out[(orow * BATCH + b) * 3 + 1] = Dy;
            out[(orow * BATCH + b) * 3 + 2] = Dz;
            Ax = Bx; Ay = By; Az = Bz;
            Bx = Cx; By = Cy; Bz = Cz;
            Cx = Dx; Cy = Dy; Cz = Dz;
        }
    }
}

// =====================================================================
extern "C" void kernel_launch(void* const* d_in, const int* in_sizes, int n_in,
                              void* d_out, int out_size, void* d_ws, size_t ws_size,
                              hipStream_t stream)
{
    const float* x       = (const float*)d_in[0];
    const float* w_ih_l0 = (const float*)d_in[1];
    const float* w_hh_l0 = (const float*)d_in[2];
    const float* b_l0    = (const float*)d_in[3];
    const float* w_ih_l1 = (const float*)d_in[4];
    const float* w_hh_l1 = (const float*)d_in[5];
    const float* b_l1    = (const float*)d_in[6];
    const float* w_lin   = (const float*)d_in[7];
    const float* b_lin   = (const float*)d_in[8];
    const float* alphabet= (const float*)d_in[9];
    (void)in_sizes; (void)n_in; (void)out_size; (void)ws_size;

    char* ws = (char*)d_ws;
    unsigned short* whhHi   = (unsigned short*)(ws + OFF_WHH_HI);
    unsigned short* whhLo   = (unsigned short*)(ws + OFF_WHH_LO);
    unsigned short* wih1Hi  = (unsigned short*)(ws + OFF_WIH1_HI);
    unsigned short* wih1Lo  = (unsigned short*)(ws + OFF_WIH1_LO);
    float*          pre     = (float*)(ws + OFF_PRE);       // pre0 then pre1 (aliased)
    uint32_t*       hFP     = (uint32_t*)(ws + OFF_H + 0 * SZ_HP);
    uint32_t*       hBP     = (uint32_t*)(ws + OFF_H + 1 * SZ_HP);
    uint32_t*       h2FP    = (uint32_t*)(ws + OFF_H + 2 * SZ_HP);
    uint32_t*       h2BP    = (uint32_t*)(ws + OFF_H + 3 * SZ_HP);
    float*          angbuf  = (float*)(ws + OFF_ANG);

    // sentinel-fill ALL h slots (0xFFFFFFFF = bf16 NaN/NaN, unreachable for
    // finite h), then zero the 4 boundary (t=0 init) slots. Write-once slots
    // + sentinel polling replace the flag protocol entirely.
    const size_t slotB = (size_t)HSLOT * 4;
    (void)hipMemsetAsync(ws + OFF_H, 0xFF, 4 * SZ_HP, stream);
    (void)hipMemsetAsync((char*)hFP, 0, slotB, stream);
    (void)hipMemsetAsync((char*)hBP + 256 * slotB, 0, slotB, stream);
    (void)hipMemsetAsync((char*)h2FP, 0, slotB, stream);
    (void)hipMemsetAsync((char*)h2BP + 256 * slotB, 0, slotB, stream);

    pack_whh_kernel<<<5000, 256, 0, stream>>>(w_hh_l0, w_hh_l1, whhHi, whhLo);
    conv_wih1_kernel<<<5000, 256, 0, stream>>>(w_ih_l1, wih1Hi, wih1Lo);
    pre0_kernel<<<1600, 256, 0, stream>>>(x, w_ih_l0, b_l0, pre);

    // layer 0 bidirectional scan
    scan_kernel<<<NBLK_SCAN, 256, 0, stream>>>(whhHi, whhLo, pre, hFP, hBP);
    // layer 1 input projection (overwrites pre in place: pre0 dead, pre1 live)
    gemm_pre1_kernel<<<800, 256, 0, stream>>>(hFP, hBP, wih1Hi, wih1Lo, b_l1, pre);
    // layer 1 bidirectional scan
    constexpr size_t LOFF = SZ_WHH_L / 2;  // ushort elements per layer
    scan_kernel<<<NBLK_SCAN, 256, 0, stream>>>(whhHi + LOFF, whhLo + LOFF, pre,
                                               h2FP, h2BP);

    head_kernel<<<L_SEQ, 256, 0, stream>>>(h2FP, h2BP, w_lin, b_lin, alphabet, angbuf);
    coords_kernel<<<1, 64, 0, stream>>>(angbuf, (float*)d_out);
}

// Round 10
// 3046.457 us; speedup vs baseline: 1.0696x; 1.0696x over previous
//
#include <hip/hip_runtime.h>
#include <stdint.h>

typedef __attribute__((ext_vector_type(8))) short short8;
typedef __attribute__((ext_vector_type(4))) float floatx4;
typedef __attribute__((ext_vector_type(4))) unsigned int uintx4;

#define DEVINL __device__ __forceinline__

DEVINL unsigned short f2bf(float f) {
    unsigned int u = __float_as_uint(f);
    u += 0x7FFFu + ((u >> 16) & 1u);
    return (unsigned short)(u >> 16);
}
DEVINL float bf2f(unsigned short h) {
    return __uint_as_float(((unsigned int)h) << 16);
}
DEVINL float sigf(float x)     { return 1.0f / (1.0f + __expf(-x)); }
DEVINL float tanhfast(float x) { return 2.0f / (1.0f + __expf(-2.0f * x)) - 1.0f; }

// ---------------- problem constants ----------------
constexpr int L_SEQ = 256, BATCH = 16, HID = 800, NGATE = 3200, DIN = 42, NALPHA = 20;
constexpr int HSLOT = BATCH * HID;          // 12800 elements per time slot
constexpr int NBLK_SCAN = 200;              // 2 dirs x 100 j-chunks (8 hidden units each)

// ---------------- workspace layout (bytes) ----------------
constexpr size_t OFF_FLAGS   = 0;                                   // reserved (unused)
constexpr size_t SZ_FLAGS    = 131072;
constexpr size_t SZ_WHH_L    = 10240000;                            // per layer: 2*3200*800*2B
constexpr size_t OFF_WHH_HI  = SZ_FLAGS;                            // 2 layers
constexpr size_t OFF_WHH_LO  = OFF_WHH_HI + 2 * SZ_WHH_L;
constexpr size_t SZ_WIH1     = 20480000;                            // 2*3200*1600*2B
constexpr size_t OFF_WIH1_HI = OFF_WHH_LO + 2 * SZ_WHH_L;
constexpr size_t OFF_WIH1_LO = OFF_WIH1_HI + SZ_WIH1;
constexpr size_t OFF_PRE     = OFF_WIH1_LO + SZ_WIH1;               // fp32, shared pre0/pre1
constexpr size_t SZ_PRE      = (size_t)2 * L_SEQ * BATCH * NGATE * 4;  // 104,857,600
constexpr size_t SZ_HP       = (size_t)257 * HSLOT * 4;             // 13,158,400 per packed buf
constexpr size_t OFF_H       = OFF_PRE + SZ_PRE;                    // 4 bufs: F, B, 2F, 2B
constexpr size_t OFF_ANG     = OFF_H + 4 * SZ_HP;                   // 256*16*3 fp32
// total ~228.6 MiB

// =====================================================================
// Pack W_hh (fp32 [2][3200][800]) into hi/lo MFMA B-fragment streams.
// =====================================================================
__global__ __launch_bounds__(256) void pack_whh_kernel(
    const float* __restrict__ w0, const float* __restrict__ w1,
    unsigned short* __restrict__ hi, unsigned short* __restrict__ lo)
{
    size_t g = (size_t)blockIdx.x * 256 + threadIdx.x;   // 1,280,000 total
    if (g >= 1280000) return;
    int l = (int)(g & 63);
    size_t gg = g >> 6;                                   // 20000 fragment ids
    int kk = (int)(gg % 25); gg /= 25;
    int nt = (int)(gg % 2);  gg /= 2;
    int jc = (int)(gg % 100); gg /= 100;
    int d  = (int)(gg % 2);
    int layer = (int)(gg / 2);
    const float* W = layer ? w1 : w0;
    int lr = nt * 16 + (l & 15);
    int gate = lr >> 3, jj = lr & 7;
    int r  = gate * 800 + jc * 8 + jj;
    int k0 = kk * 32 + (l >> 4) * 8;
    const float* s = W + ((size_t)d * NGATE + r) * HID + k0;
    short8 vh, vl;
    #pragma unroll
    for (int j = 0; j < 8; ++j) {
        float w = s[j];
        unsigned short h = f2bf(w);
        vh[j] = (short)h;
        vl[j] = (short)f2bf(w - bf2f(h));
    }
    size_t idx = (size_t)layer * 640000 + ((size_t)d * 100 + jc) * 3200
               + (size_t)(nt * 25 + kk) * 64 + l;
    ((short8*)hi)[idx] = vh;
    ((short8*)lo)[idx] = vl;
}

// =====================================================================
// fp32 -> hi/lo bf16 conversion of w_ih_l1 (flat [2][3200][1600]).
// =====================================================================
__global__ __launch_bounds__(256) void conv_wih1_kernel(
    const float* __restrict__ w, unsigned short* __restrict__ hi,
    unsigned short* __restrict__ lo)
{
    size_t g = (size_t)blockIdx.x * 256 + threadIdx.x;   // 1,280,000 groups of 8
    if (g >= 1280000) return;
    const float* s = w + g * 8;
    short8 vh, vl;
    #pragma unroll
    for (int j = 0; j < 8; ++j) {
        float x = s[j];
        unsigned short h = f2bf(x);
        vh[j] = (short)h;
        vl[j] = (short)f2bf(x - bf2f(h));
    }
    ((short8*)hi)[g] = vh;
    ((short8*)lo)[g] = vl;
}

// =====================================================================
// pre0[d][t][b][r] = x[t,b,:] @ w_ih_l0[d].T + b_l0[d]   (fp32 out)
// =====================================================================
__global__ __launch_bounds__(256) void pre0_kernel(
    const float* __restrict__ x, const float* __restrict__ wih0,
    const float* __restrict__ b0, float* __restrict__ pre0)
{
    int bid = blockIdx.x;
    int d = bid / 800; int rem = bid % 800;
    int rc = rem / 8, tc = rem % 8;
    int rbase = rc * 32, tbase = tc * 32;
    __shared__ float Wc[32][DIN];
    __shared__ float bias[32];
    __shared__ float xb[BATCH][DIN];
    int tid = threadIdx.x;
    for (int idx = tid; idx < 32 * DIN; idx += 256) {
        int rl = idx / DIN, k = idx % DIN;
        Wc[rl][k] = wih0[((size_t)d * NGATE + rbase + rl) * DIN + k];
    }
    if (tid < 32) bias[tid] = b0[d * NGATE + rbase + tid];
    __syncthreads();
    for (int tt = 0; tt < 32; ++tt) {
        int t = tbase + tt;
        for (int idx = tid; idx < BATCH * DIN; idx += 256) {
            int bb = idx / DIN, k = idx % DIN;
            xb[bb][k] = x[((size_t)bb * L_SEQ + t) * DIN + k];
        }
        __syncthreads();
        for (int o = tid; o < 512; o += 256) {
            int bb = o >> 5, rl = o & 31;
            float s = bias[rl];
            #pragma unroll 6
            for (int k = 0; k < DIN; ++k) s += xb[bb][k] * Wc[rl][k];
            pre0[((size_t)(d * L_SEQ + t) * BATCH + bb) * NGATE + rbase + rl] = s;
        }
        __syncthreads();
    }
}

// =====================================================================
// Forced-batch system-scope loads: all dwordx4 loads issued in one asm
// block (single vmcnt wait). Early-clobber outputs prevent addr aliasing.
// k-quarter variants: 14 loads (7 kk groups) and 12 loads (6 kk groups).
// =====================================================================
DEVINL void batch_load_14(const uint32_t* base, uintx4* pk) {
    asm volatile(
        "global_load_dwordx4 %0, %14, off sc0 sc1\n\t"
        "global_load_dwordx4 %1, %14, off offset:16 sc0 sc1\n\t"
        "global_load_dwordx4 %2, %14, off offset:128 sc0 sc1\n\t"
        "global_load_dwordx4 %3, %14, off offset:144 sc0 sc1\n\t"
        "global_load_dwordx4 %4, %14, off offset:256 sc0 sc1\n\t"
        "global_load_dwordx4 %5, %14, off offset:272 sc0 sc1\n\t"
        "global_load_dwordx4 %6, %14, off offset:384 sc0 sc1\n\t"
        "global_load_dwordx4 %7, %14, off offset:400 sc0 sc1\n\t"
        "global_load_dwordx4 %8, %14, off offset:512 sc0 sc1\n\t"
        "global_load_dwordx4 %9, %14, off offset:528 sc0 sc1\n\t"
        "global_load_dwordx4 %10, %14, off offset:640 sc0 sc1\n\t"
        "global_load_dwordx4 %11, %14, off offset:656 sc0 sc1\n\t"
        "global_load_dwordx4 %12, %14, off offset:768 sc0 sc1\n\t"
        "global_load_dwordx4 %13, %14, off offset:784 sc0 sc1\n\t"
        "s_waitcnt vmcnt(0)"
        : "=&v"(pk[0]), "=&v"(pk[1]), "=&v"(pk[2]), "=&v"(pk[3]),
          "=&v"(pk[4]), "=&v"(pk[5]), "=&v"(pk[6]), "=&v"(pk[7]),
          "=&v"(pk[8]), "=&v"(pk[9]), "=&v"(pk[10]), "=&v"(pk[11]),
          "=&v"(pk[12]), "=&v"(pk[13])
        : "v"(base)
        : "memory");
}

DEVINL void batch_load_12(const uint32_t* base, uintx4* pk) {
    asm volatile(
        "global_load_dwordx4 %0, %12, off sc0 sc1\n\t"
        "global_load_dwordx4 %1, %12, off offset:16 sc0 sc1\n\t"
        "global_load_dwordx4 %2, %12, off offset:128 sc0 sc1\n\t"
        "global_load_dwordx4 %3, %12, off offset:144 sc0 sc1\n\t"
        "global_load_dwordx4 %4, %12, off offset:256 sc0 sc1\n\t"
        "global_load_dwordx4 %5, %12, off offset:272 sc0 sc1\n\t"
        "global_load_dwordx4 %6, %12, off offset:384 sc0 sc1\n\t"
        "global_load_dwordx4 %7, %12, off offset:400 sc0 sc1\n\t"
        "global_load_dwordx4 %8, %12, off offset:512 sc0 sc1\n\t"
        "global_load_dwordx4 %9, %12, off offset:528 sc0 sc1\n\t"
        "global_load_dwordx4 %10, %12, off offset:640 sc0 sc1\n\t"
        "global_load_dwordx4 %11, %12, off offset:656 sc0 sc1\n\t"
        "s_waitcnt vmcnt(0)"
        : "=&v"(pk[0]), "=&v"(pk[1]), "=&v"(pk[2]), "=&v"(pk[3]),
          "=&v"(pk[4]), "=&v"(pk[5]), "=&v"(pk[6]), "=&v"(pk[7]),
          "=&v"(pk[8]), "=&v"(pk[9]), "=&v"(pk[10]), "=&v"(pk[11])
        : "v"(base)
        : "memory");
}

DEVINL void unpack_u44(uintx4 p0, uintx4 p1, short8& ah, short8& al) {
    ah[0]=(short)(p0.x&0xffffu); al[0]=(short)(p0.x>>16);
    ah[1]=(short)(p0.y&0xffffu); al[1]=(short)(p0.y>>16);
    ah[2]=(short)(p0.z&0xffffu); al[2]=(short)(p0.z>>16);
    ah[3]=(short)(p0.w&0xffffu); al[3]=(short)(p0.w>>16);
    ah[4]=(short)(p1.x&0xffffu); al[4]=(short)(p1.x>>16);
    ah[5]=(short)(p1.y&0xffffu); al[5]=(short)(p1.y>>16);
    ah[6]=(short)(p1.z&0xffffu); al[6]=(short)(p1.z>>16);
    ah[7]=(short)(p1.w&0xffffu); al[7]=(short)(p1.w>>16);
}

// k-quarter MFMA: one wave computes BOTH nt output tiles over its kk range.
template<int CNT, int KST>
DEVINL void mfma_k2(const uintx4* pk,
                    const short8* __restrict__ wH,
                    const short8* __restrict__ wL, int lane,
                    floatx4& out0, floatx4& out1)
{
    floatx4 p0 = {0.f,0.f,0.f,0.f}, q0 = {0.f,0.f,0.f,0.f};
    floatx4 p1 = {0.f,0.f,0.f,0.f}, q1 = {0.f,0.f,0.f,0.f};
    #pragma unroll
    for (int i = 0; i < CNT; ++i) {
        short8 ah, al;
        unpack_u44(pk[2 * i], pk[2 * i + 1], ah, al);
        int kk = KST + i;
        short8 bh0 = wH[(0 * 25 + kk) * 64 + lane];
        short8 bl0 = wL[(0 * 25 + kk) * 64 + lane];
        short8 bh1 = wH[(1 * 25 + kk) * 64 + lane];
        short8 bl1 = wL[(1 * 25 + kk) * 64 + lane];
        p0 = __builtin_amdgcn_mfma_f32_16x16x32_bf16(ah, bh0, p0, 0, 0, 0);
        q0 = __builtin_amdgcn_mfma_f32_16x16x32_bf16(ah, bl0, q0, 0, 0, 0);
        q0 = __builtin_amdgcn_mfma_f32_16x16x32_bf16(al, bh0, q0, 0, 0, 0);
        p1 = __builtin_amdgcn_mfma_f32_16x16x32_bf16(ah, bh1, p1, 0, 0, 0);
        q1 = __builtin_amdgcn_mfma_f32_16x16x32_bf16(ah, bl1, q1, 0, 0, 0);
        q1 = __builtin_amdgcn_mfma_f32_16x16x32_bf16(al, bh1, q1, 0, 0, 0);
    }
    out0 = p0 + q0;
    out1 = p1 + q1;
}

// =====================================================================
// Persistent bidirectional LSTM scan (split-precision bf16 hi/lo).
// R18 scan == R16 scan EXACTLY (measured 1124 us, best):
//  - sentinel protocol (data IS the signal), 4-way K-split dedup,
//  - confirmed-mask scattered poll with s_sleep(2) backoff,
//  - post-MFMA acc-NaN retry (retries rare).
// =====================================================================
__global__ __launch_bounds__(256, 1) void scan_kernel(
    const unsigned short* __restrict__ wpackH,
    const unsigned short* __restrict__ wpackL,
    const float* __restrict__ pre,              // [d][t][b][3200] fp32
    uint32_t* hFP, uint32_t* hBP)               // packed h archives [257][16][800]
{
    __shared__ __align__(16) unsigned short wldsH[25600];   // 51.2 KB
    __shared__ __align__(16) unsigned short wldsL[25600];   // 51.2 KB
    __shared__ __align__(16) float exch[2][2][4][64][4];    // [par][nt][kq][lane][reg]
    __shared__ float cbuf[128];
    int tid = threadIdx.x;
    int bid = blockIdx.x;
    int d = bid / 100, jc = bid % 100;

    {   // load weight fragments once
        const short8* sh = (const short8*)wpackH + ((size_t)d * 100 + jc) * 3200;
        const short8* sl = (const short8*)wpackL + ((size_t)d * 100 + jc) * 3200;
        short8* dh = (short8*)wldsH;
        short8* dl = (short8*)wldsL;
        for (int i = tid; i < 3200; i += 256) { dh[i] = sh[i]; dl[i] = sl[i]; }
    }
    if (tid < 128) cbuf[tid] = 0.0f;
    __syncthreads();

    int lane = tid & 63, w = tid >> 6;          // w = k-quarter index
    int st = 6 * w + (w > 0 ? 1 : 0);           // kkStart: {0,7,13,19}
    int bA = lane & 15, q = lane >> 4;
    int fb = (tid >> 3) & 15, fj = tid & 7;     // fuse indices (tid<128)

    uint32_t* hOutP = d ? hBP : hFP;
    const uint32_t* hInP = d ? hBP : hFP;
    const short8* wH8 = (const short8*)wldsH;
    const short8* wL8 = (const short8*)wldsL;

    // Poll setup: wave w's k-range [st*32, (st+CNT)*32) is produced by
    // jc blocks [jcBase, jcBase+npoll). Lane l checks jc jx's first word
    // (batch jx&15 scatters lines). Loop-invariant offset within a slot.
    int npoll = (w == 0) ? 28 : 24;
    int jcBase = (w == 0) ? 0 : (4 + 24 * w);   // {0,28,52,76}
    int jx = jcBase + ((lane < npoll) ? lane : 0);
    size_t pofs = (size_t)(jx & 15) * HID + (size_t)jx * 8;

    for (int s = 0; s < L_SEQ; ++s) {
        int t = d ? (L_SEQ - 1 - s) : s;
        int islot = d ? (t + 1) : t;
        const uint32_t* slotBase = hInP + (size_t)islot * HSLOT;
        const uint32_t* base = slotBase + bA * HID + st * 32 + q * 8;

        // prefetch pre gate values (independent of h) before waiting
        float pv[4];
        if (tid < 128) {
            const float* pp = pre + ((size_t)(d * L_SEQ + t) * BATCH + fb) * NGATE
                            + jc * 8 + fj;
            #pragma unroll
            for (int gate = 0; gate < 4; ++gate) pv[gate] = pp[gate * 800];
        }

        // ---- arrival poll on the h data itself (confirmed-mask + backoff) ----
        {
            const uint32_t* pw = slotBase + pofs;
            bool need = (lane < npoll);
            for (;;) {
                if (need) {
                    uint32_t v = __hip_atomic_load(pw, __ATOMIC_RELAXED,
                                                   __HIP_MEMORY_SCOPE_AGENT);
                    need = (v == 0xFFFFFFFFu);
                }
                if (!__any(need)) break;
                __builtin_amdgcn_s_sleep(2);
            }
        }

        // ---- batch load + split MFMA; NaN acc => raced a straggler => retry
        uintx4 pk[14];
        floatx4 acc0, acc1;
        for (;;) {
            if (w == 0) {
                batch_load_14(base, pk);
                mfma_k2<7, 0 >(pk, wH8, wL8, lane, acc0, acc1);
            } else if (w == 1) {
                batch_load_12(base, pk);
                mfma_k2<6, 7 >(pk, wH8, wL8, lane, acc0, acc1);
            } else if (w == 2) {
                batch_load_12(base, pk);
                mfma_k2<6, 13>(pk, wH8, wL8, lane, acc0, acc1);
            } else {
                batch_load_12(base, pk);
                mfma_k2<6, 19>(pk, wH8, wL8, lane, acc0, acc1);
            }
            bool bad = (acc0[0] != acc0[0]) || (acc0[1] != acc0[1])
                     || (acc0[2] != acc0[2]) || (acc0[3] != acc0[3])
                     || (acc1[0] != acc1[0]) || (acc1[1] != acc1[1])
                     || (acc1[2] != acc1[2]) || (acc1[3] != acc1[3]);
            if (!__any(bad)) break;
        }

        int p = s & 1;
        *(floatx4*)&exch[p][0][w][lane][0] = acc0;
        *(floatx4*)&exch[p][1][w][lane][0] = acc1;
        __syncthreads();     // the ONE barrier per step

        if (tid < 128) {
            float G[4];
            #pragma unroll
            for (int gate = 0; gate < 4; ++gate) {
                int lr = gate * 8 + fj;
                int nt2 = lr >> 4, n = lr & 15;
                int ln = ((fb >> 2) << 4) | n;
                int rg = fb & 3;
                G[gate] = pv[gate]
                        + exch[p][nt2][0][ln][rg] + exch[p][nt2][1][ln][rg]
                        + exch[p][nt2][2][ln][rg] + exch[p][nt2][3][ln][rg];
            }
            float i_ = sigf(G[0]), f_ = sigf(G[1]);
            float g_ = tanhfast(G[2]), o_ = sigf(G[3]);
            float c = f_ * cbuf[tid] + i_ * g_;
            cbuf[tid] = c;
            float h = o_ * tanhfast(c);
            int oslot = d ? t : (t + 1);
            size_t oidx = (size_t)oslot * HSLOT + fb * HID + jc * 8 + fj;
            unsigned short hh = f2bf(h);
            uint32_t pko = (uint32_t)hh
                         | ((uint32_t)f2bf(h - bf2f(hh)) << 16);
            __hip_atomic_store(&hOutP[oidx], pko, __ATOMIC_RELAXED,
                               __HIP_MEMORY_SCOPE_AGENT);
            // no drain, no flag: consumers poll the data itself
        }
        // no trailing barrier: exch double-buffered; next-step barrier orders reuse
    }
}

// =====================================================================
// pre1[d][t][b][r] = concat(h1f[t], h1b[t]) @ w_ih_l1[d].T + b_l1[d]  (fp32)
// R18: REVERTED to the R13/R16 128x128 tile (proven best: 4 blocks/CU,
// 38.9 KB LDS; R17's 256x128 cost +188us via occupancy quantization).
// Register-prefetch software pipeline (kk+1 loads under kk's MFMAs).
// =====================================================================
__global__ __launch_bounds__(256, 1) void gemm_pre1_kernel(
    const uint32_t* __restrict__ hFP, const uint32_t* __restrict__ hBP,
    const unsigned short* __restrict__ wih1H, const unsigned short* __restrict__ wih1L,
    const float* __restrict__ b1, float* __restrict__ pre1)
{
    int bid = blockIdx.x;
    int d = bid / 800; int rst = bid % 800;
    int mblk = rst / 25, nblk = rst % 25;
    __shared__ __align__(16) uint32_t       Au[128][36];   // packed h (hi|lo<<16)
    __shared__ __align__(16) unsigned short BH[128][40];
    __shared__ __align__(16) unsigned short BL[128][40];
    int tid = threadIdx.x, lane = tid & 63, w = tid >> 6;
    int wm = w >> 1, wn = w & 1;
    floatx4 acc[4][4] = {};
    int row = tid >> 1, half = tid & 1;         // staging: 2 threads/row
    int m_row = mblk * 128 + row;
    int t = m_row >> 4, bb = m_row & 15;
    int la = lane & 15, q = lane >> 4, q8 = q * 8;

    uintx4 ra[4];
    short8 rbh[2], rbl[2];

    auto LOAD = [&](int kk) {
        int k0 = kk * 32 + half * 16;
        size_t aoff = (kk < 25)
            ? ((size_t)(t + 1) * HSLOT + bb * HID + k0)
            : ((size_t)t * HSLOT + bb * HID + (k0 - 800));
        const uintx4* ap = (const uintx4*)(((kk < 25) ? hFP : hBP) + aoff);
        ra[0] = ap[0]; ra[1] = ap[1]; ra[2] = ap[2]; ra[3] = ap[3];
        size_t boff = ((size_t)d * NGATE + nblk * 128 + row) * 1600
                    + (size_t)kk * 32 + half * 16;
        const short8* bh = (const short8*)(wih1H + boff);
        const short8* bl = (const short8*)(wih1L + boff);
        rbh[0] = bh[0]; rbh[1] = bh[1];
        rbl[0] = bl[0]; rbl[1] = bl[1];
    };

    LOAD(0);
    for (int kk = 0; kk < 50; ++kk) {
        {   // commit staged regs to LDS
            uintx4* da = (uintx4*)&Au[row][half * 16];
            da[0] = ra[0]; da[1] = ra[1]; da[2] = ra[2]; da[3] = ra[3];
            short8* dh = (short8*)&BH[row][half * 16];
            dh[0] = rbh[0]; dh[1] = rbh[1];
            short8* dl = (short8*)&BL[row][half * 16];
            dl[0] = rbl[0]; dl[1] = rbl[1];
        }
        __syncthreads();
        if (kk < 49) LOAD(kk + 1);          // global latency hides under MFMAs
        #pragma unroll
        for (int ms = 0; ms < 4; ++ms) {
            const uintx4* pa = (const uintx4*)&Au[wm * 64 + ms * 16 + la][q8];
            short8 ah, al;
            unpack_u44(pa[0], pa[1], ah, al);
            #pragma unroll
            for (int ns = 0; ns < 4; ++ns) {
                short8 fbh = *(const short8*)&BH[wn * 64 + ns * 16 + la][q8];
                short8 fbl = *(const short8*)&BL[wn * 64 + ns * 16 + la][q8];
                acc[ms][ns] = __builtin_amdgcn_mfma_f32_16x16x32_bf16(ah, fbh, acc[ms][ns], 0, 0, 0);
                acc[ms][ns] = __builtin_amdgcn_mfma_f32_16x16x32_bf16(ah, fbl, acc[ms][ns], 0, 0, 0);
                acc[ms][ns] = __builtin_amdgcn_mfma_f32_16x16x32_bf16(al, fbh, acc[ms][ns], 0, 0, 0);
            }
        }
        __syncthreads();
    }
    #pragma unroll
    for (int ms = 0; ms < 4; ++ms)
        #pragma unroll
        for (int ns = 0; ns < 4; ++ns)
            #pragma unroll
            for (int rg = 0; rg < 4; ++rg) {
                int m = mblk * 128 + wm * 64 + ms * 16 + q * 4 + rg;
                int t2 = m >> 4, b2 = m & 15;
                int r = nblk * 128 + wn * 64 + ns * 16 + la;
                float val = acc[ms][ns][rg] + b1[d * NGATE + r];
                pre1[((size_t)(d * L_SEQ + t2) * BATCH + b2) * NGATE + r] = val;
            }
}

// =====================================================================
// Head: logits -> softmax -> torsion angles.  One block per t.
// R18: inner k-loop vectorized (uint4/float4, 4 elems/load) -- bases
// 16B-aligned (800, 1600, 12800 all %4==0).
// =====================================================================
__global__ __launch_bounds__(256) void head_kernel(
    const uint32_t* __restrict__ h2FP, const uint32_t* __restrict__ h2BP,
    const float* __restrict__ wlin, const float* __restrict__ blin,
    const float* __restrict__ alphabet, float* __restrict__ ang)
{
    int t = blockIdx.x, tid = threadIdx.x;
    __shared__ float lg[BATCH * NALPHA];
    __shared__ float probs[BATCH * NALPHA];
    for (int i = tid; i < BATCH * NALPHA; i += 256) {
        int a = i % NALPHA, b = i / NALPHA;
        size_t fo = (size_t)(t + 1) * HSLOT + b * HID;
        size_t bo = (size_t)t * HSLOT + b * HID;
        const uint4*   pf = (const uint4*)(h2FP + fo);
        const uint4*   pb = (const uint4*)(h2BP + bo);
        const float4*  wf = (const float4*)(wlin + (size_t)a * 1600);
        const float4*  wb = (const float4*)(wlin + (size_t)a * 1600 + 800);
        float s = blin[a];
        #pragma unroll 2
        for (int k4 = 0; k4 < HID / 4; ++k4) {
            uint4  uf = pf[k4], ub = pb[k4];
            float4 wa = wf[k4], wc = wb[k4];
            s += (bf2f((unsigned short)uf.x) + bf2f((unsigned short)(uf.x >> 16))) * wa.x
               + (bf2f((unsigned short)uf.y) + bf2f((unsigned short)(uf.y >> 16))) * wa.y
               + (bf2f((unsigned short)uf.z) + bf2f((unsigned short)(uf.z >> 16))) * wa.z
               + (bf2f((unsigned short)uf.w) + bf2f((unsigned short)(uf.w >> 16))) * wa.w
               + (bf2f((unsigned short)ub.x) + bf2f((unsigned short)(ub.x >> 16))) * wc.x
               + (bf2f((unsigned short)ub.y) + bf2f((unsigned short)(ub.y >> 16))) * wc.y
               + (bf2f((unsigned short)ub.z) + bf2f((unsigned short)(ub.z >> 16))) * wc.z
               + (bf2f((unsigned short)ub.w) + bf2f((unsigned short)(ub.w >> 16))) * wc.w;
        }
        lg[b * NALPHA + a] = s;
    }
    __syncthreads();
    if (tid < BATCH) {
        int b = tid;
        float mx = -1e30f;
        for (int a = 0; a < NALPHA; ++a) mx = fmaxf(mx, lg[b * NALPHA + a]);
        float sum = 0.f;
        for (int a = 0; a < NALPHA; ++a) {
            float e = __expf(lg[b * NALPHA + a] - mx);
            probs[b * NALPHA + a] = e; sum += e;
        }
        float inv = 1.0f / sum;
        for (int a = 0; a < NALPHA; ++a) probs[b * NALPHA + a] *= inv;
    }
    __syncthreads();
    if (tid < BATCH * 3) {
        int b = tid / 3, i = tid % 3;
        float ss = 0.f, cc = 0.f;
        for (int a = 0; a < NALPHA; ++a) {
            float al = alphabet[a * 3 + i], p = probs[b * NALPHA + a];
            ss += p * sinf(al); cc += p * cosf(al);
        }
        ang[((size_t)t * BATCH + b) * 3 + i] = atan2f(ss, cc);
    }
}

// =====================================================================
// Sequential NeRF coordinate chain. One block; lane b handles batch b.
// Fast HW trig (__sinf/__cosf, P in [-pi,pi]) + rsqrtf.  [R13, kept]
// =====================================================================
__global__ __launch_bounds__(64) void coords_kernel(
    const float* __restrict__ ang, float* __restrict__ out)
{
    int b = threadIdx.x;
    if (b >= BATCH) return;
    const float LENS[3] = {145.801f, 152.326f, 132.868f};
    const float ANGS[3] = {2.124f, 1.941f, 2.028f};
    float sT[3], cT[3];
    #pragma unroll
    for (int i = 0; i < 3; ++i) { sT[i] = sinf(ANGS[i]); cT[i] = cosf(ANGS[i]); }
    float Ax = 0.f, Ay = 0.f, Az = 1.f;
    float Bx = 0.f, By = 1.f, Bz = 0.f;
    float Cx = 1.f, Cy = 0.f, Cz = 0.f;
    out[((size_t)0 * BATCH + b) * 3 + 0] = 0.f; out[((size_t)0 * BATCH + b) * 3 + 1] = 0.f; out[((size_t)0 * BATCH + b) * 3 + 2] = 1.f;
    out[((size_t)1 * BATCH + b) * 3 + 0] = 0.f; out[((size_t)1 * BATCH + b) * 3 + 1] = 1.f; out[((size_t)1 * BATCH + b) * 3 + 2] = 0.f;
    out[((size_t)2 * BATCH + b) * 3 + 0] = 1.f; out[((size_t)2 * BATCH + b) * 3 + 1] = 0.f; out[((size_t)2 * BATCH + b) * 3 + 2] = 0.f;
    for (int t = 0; t < L_SEQ; ++t) {
        #pragma unroll
        for (int i = 0; i < 3; ++i) {
            float P = ang[((size_t)t * BATCH + b) * 3 + i];
            float R = LENS[i];
            float sP = __sinf(P), cP = __cosf(P);
            float D2x = -R * cT[i];
            float D2y = R * cP * sT[i];
            float D2z = R * sP * sT[i];
            float bx = Cx - Bx, by = Cy - By, bz = Cz - Bz;
            float binv = rsqrtf(bx * bx + by * by + bz * bz);
            bx *= binv; by *= binv; bz *= binv;
            float ux = Bx - Ax, uy = By - Ay, uz = Bz - Az;
            float nx = uy * bz - uz * by;
            float ny = uz * bx - ux * bz;
            float nz = ux * by - uy * bx;
            float ninv = rsqrtf(nx * nx + ny * ny + nz * nz);
            nx *= ninv; ny *= ninv; nz *= ninv;
            float cxx = ny * bz - nz * by;
            float cxy = nz * bx - nx * bz;
            float cxz = nx * by - ny * bx;
            float Dx = bx * D2x + cxx * D2y + nx * D2z + Cx;
            float Dy = by * D2x + cxy * D2y + ny * D2z + Cy;
            float Dz = bz * D2x + cxz * D2y + nz * D2z + Cz;
            size_t orow = 3 + (size_t)t * 3 + i;
            out[(orow * BATCH + b) * 3 + 0] = Dx;
            out[(orow * BATCH + b) * 3 + 1] = Dy;
            out[(orow * BATCH + b) * 3 + 2] = Dz;
            Ax = Bx; Ay = By; Az = Bz;
            Bx = Cx; By = Cy; Bz = Cz;
            Cx = Dx; Cy = Dy; Cz = Dz;
        }
    }
}

// =====================================================================
extern "C" void kernel_launch(void* const* d_in, const int* in_sizes, int n_in,
                              void* d_out, int out_size, void* d_ws, size_t ws_size,
                              hipStream_t stream)
{
    const float* x       = (const float*)d_in[0];
    const float* w_ih_l0 = (const float*)d_in[1];
    const float* w_hh_l0 = (const float*)d_in[2];
    const float* b_l0    = (const float*)d_in[3];
    const float* w_ih_l1 = (const float*)d_in[4];
    const float* w_hh_l1 = (const float*)d_in[5];
    const float* b_l1    = (const float*)d_in[6];
    const float* w_lin   = (const float*)d_in[7];
    const float* b_lin   = (const float*)d_in[8];
    const float* alphabet= (const float*)d_in[9];
    (void)in_sizes; (void)n_in; (void)out_size; (void)ws_size;

    char* ws = (char*)d_ws;
    unsigned short* whhHi   = (unsigned short*)(ws + OFF_WHH_HI);
    unsigned short* whhLo   = (unsigned short*)(ws + OFF_WHH_LO);
    unsigned short* wih1Hi  = (unsigned short*)(ws + OFF_WIH1_HI);
    unsigned short* wih1Lo  = (unsigned short*)(ws + OFF_WIH1_LO);
    float*          pre     = (float*)(ws + OFF_PRE);       // pre0 then pre1 (aliased)
    uint32_t*       hFP     = (uint32_t*)(ws + OFF_H + 0 * SZ_HP);
    uint32_t*       hBP     = (uint32_t*)(ws + OFF_H + 1 * SZ_HP);
    uint32_t*       h2FP    = (uint32_t*)(ws + OFF_H + 2 * SZ_HP);
    uint32_t*       h2BP    = (uint32_t*)(ws + OFF_H + 3 * SZ_HP);
    float*          angbuf  = (float*)(ws + OFF_ANG);

    // sentinel-fill ALL h slots (0xFFFFFFFF = bf16 NaN/NaN, unreachable for
    // finite h), then zero the 4 boundary (t=0 init) slots. Write-once slots
    // + sentinel polling replace the flag protocol entirely.
    const size_t slotB = (size_t)HSLOT * 4;
    (void)hipMemsetAsync(ws + OFF_H, 0xFF, 4 * SZ_HP, stream);
    (void)hipMemsetAsync((char*)hFP, 0, slotB, stream);
    (void)hipMemsetAsync((char*)hBP + 256 * slotB, 0, slotB, stream);
    (void)hipMemsetAsync((char*)h2FP, 0, slotB, stream);
    (void)hipMemsetAsync((char*)h2BP + 256 * slotB, 0, slotB, stream);

    pack_whh_kernel<<<5000, 256, 0, stream>>>(w_hh_l0, w_hh_l1, whhHi, whhLo);
    conv_wih1_kernel<<<5000, 256, 0, stream>>>(w_ih_l1, wih1Hi, wih1Lo);
    pre0_kernel<<<1600, 256, 0, stream>>>(x, w_ih_l0, b_l0, pre);

    // layer 0 bidirectional scan
    scan_kernel<<<NBLK_SCAN, 256, 0, stream>>>(whhHi, whhLo, pre, hFP, hBP);
    // layer 1 input projection (overwrites pre in place: pre0 dead, pre1 live)
    gemm_pre1_kernel<<<1600, 256, 0, stream>>>(hFP, hBP, wih1Hi, wih1Lo, b_l1, pre);
    // layer 1 bidirectional scan
    constexpr size_t LOFF = SZ_WHH_L / 2;  // ushort elements per layer
    scan_kernel<<<NBLK_SCAN, 256, 0, stream>>>(whhHi + LOFF, whhLo + LOFF, pre,
                                               h2FP, h2BP);

    head_kernel<<<L_SEQ, 256, 0, stream>>>(h2FP, h2BP, w_lin, b_lin, alphabet, angbuf);
    coords_kernel<<<1, 64, 0, stream>>>(angbuf, (float*)d_out);
}